// Round 4
// baseline (287.691 us; speedup 1.0000x reference)
//
#include <hip/hip_runtime.h>
#include <stdint.h>

#define FP8_MAX 448.0f
// Problem dims (fixed per setup_inputs): B=4, D=64, H=16, N=2048
#define NB 4
#define ND 64
#define NH 16
#define NS 2048

typedef float f32x4 __attribute__((ext_vector_type(4)));

// ---------------------------------------------------------------------------
// Pass 1: per-tensor abs-max (ONE tensor per launch so the immediately
// following quant pass re-reads it out of the 256MB L3, not HBM).
// Result stored as monotonic uint bits (valid max-order for non-negative f32).
// ---------------------------------------------------------------------------
__global__ __launch_bounds__(256) void amax_kernel(const float* __restrict__ x,
                                                   unsigned* __restrict__ slot,
                                                   int n4) {
  const float4* src = (const float4*)x;
  float m = 0.f;
  for (int i = blockIdx.x * 256 + threadIdx.x; i < n4; i += gridDim.x * 256) {
    float4 v = src[i];
    m = fmaxf(m, fmaxf(fmaxf(fabsf(v.x), fabsf(v.y)), fmaxf(fabsf(v.z), fabsf(v.w))));
  }
#pragma unroll
  for (int off = 32; off > 0; off >>= 1)
    m = fmaxf(m, __shfl_xor(m, off, 64));

  __shared__ float red[4];
  if ((threadIdx.x & 63) == 0) red[threadIdx.x >> 6] = m;
  __syncthreads();
  if (threadIdx.x == 0) {
    m = fmaxf(fmaxf(red[0], red[1]), fmaxf(red[2], red[3]));
    atomicMax(slot, __float_as_uint(m));
  }
}

// ---------------------------------------------------------------------------
// Pass 2: quantize to fp8 e4m3 (RNE via v_cvt_pk_fp8_f32) AND repack into the
// fragment-packed layout for mfma_f32_16x16x32_fp8_fp8:
//   chunk index c = (((bh*128 + rg)*2 + ks)*64 + kg*16 + r16)  (8B chunks)
//   chunk holds d = ks*32 + kg*8 .. +7   of row n = rg*16 + r16
// Vectorized: each thread handles 4 consecutive rows (r16 = r4*4+q) x 8 d:
//   reads 8 x float4 (16B/lane, 64B segments), writes 4 chunks = 32B contig.
// Thread id t (18 bits): r4[0:1] kg[2:3] ks[4] rg[5:11] bh[12:17].
// ---------------------------------------------------------------------------
__global__ __launch_bounds__(256) void quant_kernel(const float* __restrict__ in,
                                                    uint2* __restrict__ outp,
                                                    const unsigned* __restrict__ amaxbits) {
  const unsigned t = blockIdx.x * 256 + threadIdx.x;  // [0, 2^18)
  const float amax  = fmaxf(__uint_as_float(*amaxbits), 1e-12f);
  const float scale = FP8_MAX / amax;

  const unsigned r4 = t & 3;
  const unsigned kg = (t >> 2) & 3;
  const unsigned ks = (t >> 4) & 1;
  const unsigned rg = (t >> 5) & 127;
  const unsigned bh = t >> 12;
  const unsigned d0 = ks * 32 + kg * 8;
  const unsigned nb = rg * 16 + r4 * 4;  // first of 4 consecutive rows
  const unsigned b  = bh >> 4, h = bh & 15;

  const float4* src = (const float4*)(in + (size_t)(b * ND + d0) * (NH * NS) + h * NS + nb);

  float4 ld[8];
#pragma unroll
  for (int j = 0; j < 8; ++j)
    ld[j] = src[(size_t)j * (NH * NS / 4)];  // d0+j, rows nb..nb+3

  const unsigned cb = ((bh * 128 + rg) * 2 + ks) * 64 + kg * 16 + r4 * 4;
  uint2 ch[4];
#pragma unroll
  for (int q = 0; q < 4; ++q) {
    float v[8];
#pragma unroll
    for (int j = 0; j < 8; ++j) {
      float x = (&ld[j].x)[q] * scale;
      v[j] = fminf(fmaxf(x, -FP8_MAX), FP8_MAX);
    }
    unsigned lo = 0, hi = 0;
    lo = __builtin_amdgcn_cvt_pk_fp8_f32(v[0], v[1], lo, 0);
    lo = __builtin_amdgcn_cvt_pk_fp8_f32(v[2], v[3], lo, 1);
    hi = __builtin_amdgcn_cvt_pk_fp8_f32(v[4], v[5], hi, 0);
    hi = __builtin_amdgcn_cvt_pk_fp8_f32(v[6], v[7], hi, 1);
    ch[q] = make_uint2(lo, hi);
  }
  // 32B contiguous store (two uint4s)
  uint4* dst = (uint4*)&outp[cb];
  dst[0] = make_uint4(ch[0].x, ch[0].y, ch[1].x, ch[1].y);
  dst[1] = make_uint4(ch[2].x, ch[2].y, ch[3].x, ch[3].y);
}

// ---------------------------------------------------------------------------
// Pass 3: batched GEMM  S[bh][n][m] = sum_d Q[bh][n][d] * K[bh][m][d]
// 128x128 tile per block, 4 waves (2x2, each 64x64 = 4x4 frags of 16x16).
// LDS-staged (each tile read ONCE from global: contiguous 8KB copy), with
// fragment-packed LDS layout so ds_read_b64 is lane-contiguous (2-way bank
// pattern = free).  Operand swap (A=K, B=Q) makes D's reg index walk m (the
// fast output dim) -> plain f32x4 stores, 64B segments, L2 write-combined.
// __launch_bounds__(256,4): target <=128 VGPR -> 4 blocks/CU so one block's
// store burst overlaps the next block's staging.
// ---------------------------------------------------------------------------
__global__ __launch_bounds__(256, 4) void gemm_kernel(const long long* __restrict__ qp,
                                                      const long long* __restrict__ kp,
                                                      float* __restrict__ out,
                                                      const unsigned* __restrict__ amaxbits) {
  __shared__ __align__(16) long long ldsA[1024];  // 8KB: 8 row-groups x 2 ks x 64 chunks
  __shared__ __align__(16) long long ldsB[1024];

  const int tid  = threadIdx.x;
  const int lane = tid & 63;
  const int wid  = tid >> 6;
  const int wm   = wid >> 1;  // n-half (0..1)
  const int wn   = wid & 1;   // m-half (0..1)

  const int bh = blockIdx.z;
  const int n0 = blockIdx.y * 128;
  const int m0 = blockIdx.x * 128;

  // Fragment-packed global tiles are contiguous: 8 row-groups * 128 chunks.
  const long long* Ag = qp + ((size_t)bh * 128 + (n0 >> 4)) * 128;
  const long long* Bg = kp + ((size_t)bh * 128 + (m0 >> 4)) * 128;

#pragma unroll
  for (int i = 0; i < 2; ++i) {
    int g = i * 512 + tid * 2;  // 16B per thread per iter
    *(uint4*)&ldsA[g] = *(const uint4*)&Ag[g];
    *(uint4*)&ldsB[g] = *(const uint4*)&Bg[g];
  }
  __syncthreads();

  const int r16 = lane & 15;
  const int kg  = lane >> 4;

  long long qfrag[2][4], kfrag[2][4];
#pragma unroll
  for (int ks = 0; ks < 2; ++ks) {
#pragma unroll
    for (int f = 0; f < 4; ++f) {
      qfrag[ks][f] = ldsA[((wm * 4 + f) * 2 + ks) * 64 + lane];
      kfrag[ks][f] = ldsB[((wn * 4 + f) * 2 + ks) * 64 + lane];
    }
  }

  f32x4 acc[4][4] = {};  // [i = m-frag][j = n-frag]
#pragma unroll
  for (int ks = 0; ks < 2; ++ks)
#pragma unroll
    for (int i = 0; i < 4; ++i)
#pragma unroll
      for (int j = 0; j < 4; ++j)
        acc[i][j] = __builtin_amdgcn_mfma_f32_16x16x32_fp8_fp8(kfrag[ks][i], qfrag[ks][j],
                                                               acc[i][j], 0, 0, 0);

  // dequant: S = (raw fp8 dot) * amax_q*amax_k/(448^2) / sqrt(64)
  const float aq = fmaxf(__uint_as_float(amaxbits[0]), 1e-12f);
  const float ak = fmaxf(__uint_as_float(amaxbits[1]), 1e-12f);
  const float dq = aq * ak / (FP8_MAX * FP8_MAX * 8.0f);

  float* outbh = out + (size_t)bh * NS * NS;
#pragma unroll
  for (int j = 0; j < 4; ++j) {
    const int n = n0 + wm * 64 + j * 16 + r16;
#pragma unroll
    for (int i = 0; i < 4; ++i) {
      const int m = m0 + wn * 64 + i * 16 + kg * 4;
      f32x4 v;
#pragma unroll
      for (int r = 0; r < 4; ++r) v[r] = acc[i][j][r] * dq;
      *(f32x4*)(outbh + (size_t)n * NS + m) = v;
    }
  }
}

// ---------------------------------------------------------------------------
extern "C" void kernel_launch(void* const* d_in, const int* in_sizes, int n_in,
                              void* d_out, int out_size, void* d_ws, size_t ws_size,
                              hipStream_t stream) {
  const float* q = (const float*)d_in[0];
  const float* k = (const float*)d_in[1];
  float* out = (float*)d_out;

  // ws layout: [0..7] amax bits (q,k) | @256: fp8 Qp (8MB) | fp8 Kp (8MB)
  unsigned* amax = (unsigned*)d_ws;
  unsigned char* qp = (unsigned char*)d_ws + 256;
  unsigned char* kp = qp + (size_t)NB * NH * NS * ND;  // 8,388,608

  hipMemsetAsync(amax, 0, 8, stream);

  const int n4 = in_sizes[0] / 4;  // float4 count per tensor

  // Per-tensor ordering: quant_X immediately follows amax_X so the 134MB
  // tensor is still L3-resident (256MB) for the re-read.
  amax_kernel<<<1024, 256, 0, stream>>>(q, amax, n4);
  quant_kernel<<<1024, 256, 0, stream>>>(q, (uint2*)qp, amax);
  amax_kernel<<<1024, 256, 0, stream>>>(k, amax + 1, n4);
  quant_kernel<<<1024, 256, 0, stream>>>(k, (uint2*)kp, amax + 1);

  dim3 grid(NS / 128, NS / 128, NB * NH);  // (m-tiles, n-tiles, bh)
  gemm_kernel<<<grid, 256, 0, stream>>>((const long long*)qp, (const long long*)kp, out, amax);
}

// Round 5
// 271.928 us; speedup vs baseline: 1.0580x; 1.0580x over previous
//
#include <hip/hip_runtime.h>
#include <stdint.h>

#define FP8_MAX 448.0f
// Problem dims (fixed per setup_inputs): B=4, D=64, H=16, N=2048
#define NB 4
#define ND 64
#define NH 16
#define NS 2048

typedef float f32x4 __attribute__((ext_vector_type(4)));

// ---------------------------------------------------------------------------
// Pass 1: per-tensor abs-max (ONE tensor per launch so the immediately
// following quant pass re-reads it out of the 256MB L3, not HBM).
// Result stored as monotonic uint bits (valid max-order for non-negative f32).
// ---------------------------------------------------------------------------
__global__ __launch_bounds__(256) void amax_kernel(const float* __restrict__ x,
                                                   unsigned* __restrict__ slot,
                                                   int n4) {
  const float4* src = (const float4*)x;
  float m = 0.f;
  for (int i = blockIdx.x * 256 + threadIdx.x; i < n4; i += gridDim.x * 256) {
    float4 v = src[i];
    m = fmaxf(m, fmaxf(fmaxf(fabsf(v.x), fabsf(v.y)), fmaxf(fabsf(v.z), fabsf(v.w))));
  }
#pragma unroll
  for (int off = 32; off > 0; off >>= 1)
    m = fmaxf(m, __shfl_xor(m, off, 64));

  __shared__ float red[4];
  if ((threadIdx.x & 63) == 0) red[threadIdx.x >> 6] = m;
  __syncthreads();
  if (threadIdx.x == 0) {
    m = fmaxf(fmaxf(red[0], red[1]), fmaxf(red[2], red[3]));
    atomicMax(slot, __float_as_uint(m));
  }
}

// ---------------------------------------------------------------------------
// Pass 2: quantize to fp8 e4m3 (RNE via v_cvt_pk_fp8_f32) AND repack into a
// fragment-packed layout for mfma_f32_16x16x32_fp8_fp8:
//   chunk index c = (((bh*128 + rg)*2 + ks)*64 + kg*16 + r16)  (8B chunks)
//   chunk holds d = ks*32 + kg*8 .. +7   of row n = rg*16 + r16
// Scalar-load form (R3): lanes 0-15 read 16 consecutive n (64B contiguous),
// full 64B line utilization, 256B/instr per wave.  (R4's float4 variant was
// neutral-at-best; keeping the version with the known-good measurement.)
// ---------------------------------------------------------------------------
__global__ __launch_bounds__(256) void quant_kernel(const float* __restrict__ in,
                                                    uint2* __restrict__ outp,
                                                    const unsigned* __restrict__ amaxbits) {
  const unsigned c = blockIdx.x * 256 + threadIdx.x;  // [0, 2^20)
  const float amax  = fmaxf(__uint_as_float(*amaxbits), 1e-12f);
  const float scale = FP8_MAX / amax;

  const unsigned r16 = c & 15;
  const unsigned kg  = (c >> 4) & 3;
  const unsigned ks  = (c >> 6) & 1;
  const unsigned rg  = (c >> 7) & 127;
  const unsigned bh  = c >> 14;
  const unsigned n   = rg * 16 + r16;
  const unsigned d0  = ks * 32 + kg * 8;
  const unsigned b   = bh >> 4, h = bh & 15;

  const float* src = in + (size_t)(b * ND + d0) * (NH * NS) + h * NS + n;

  float v[8];
#pragma unroll
  for (int j = 0; j < 8; ++j) {
    float x = src[(size_t)j * (NH * NS)] * scale;
    v[j] = fminf(fmaxf(x, -FP8_MAX), FP8_MAX);
  }
  unsigned lo = 0, hi = 0;
  lo = __builtin_amdgcn_cvt_pk_fp8_f32(v[0], v[1], lo, 0);
  lo = __builtin_amdgcn_cvt_pk_fp8_f32(v[2], v[3], lo, 1);
  hi = __builtin_amdgcn_cvt_pk_fp8_f32(v[4], v[5], hi, 0);
  hi = __builtin_amdgcn_cvt_pk_fp8_f32(v[6], v[7], hi, 1);
  outp[c] = make_uint2(lo, hi);
}

// ---------------------------------------------------------------------------
// Pass 3: batched GEMM  S[bh][n][m] = sum_d Q[bh][n][d] * K[bh][m][d]
// 128x128 tile per block, 4 waves (2x2, each 64x64 = 4x4 frags of 16x16).
// LDS-staged (each tile read ONCE from global: contiguous 8KB copy), with
// fragment-packed LDS layout so ds_read_b64 is lane-contiguous (2-way bank
// pattern = free).  Operand swap (A=K, B=Q) makes D's reg index walk m (the
// fast output dim) -> plain f32x4 stores, 64B segments, L2 write-combined.
// NO launch_bounds occupancy cap: R4 showed (256,4) forces VGPR<=128 ->
// spills -> +15us of scratch traffic across 16384 blocks.
// ---------------------------------------------------------------------------
__global__ __launch_bounds__(256) void gemm_kernel(const long long* __restrict__ qp,
                                                   const long long* __restrict__ kp,
                                                   float* __restrict__ out,
                                                   const unsigned* __restrict__ amaxbits) {
  __shared__ __align__(16) long long ldsA[1024];  // 8KB: 8 row-groups x 2 ks x 64 chunks
  __shared__ __align__(16) long long ldsB[1024];

  const int tid  = threadIdx.x;
  const int lane = tid & 63;
  const int wid  = tid >> 6;
  const int wm   = wid >> 1;  // n-half (0..1)
  const int wn   = wid & 1;   // m-half (0..1)

  const int bh = blockIdx.z;
  const int n0 = blockIdx.y * 128;
  const int m0 = blockIdx.x * 128;

  // Fragment-packed global tiles are contiguous: 8 row-groups * 128 chunks.
  const long long* Ag = qp + ((size_t)bh * 128 + (n0 >> 4)) * 128;
  const long long* Bg = kp + ((size_t)bh * 128 + (m0 >> 4)) * 128;

#pragma unroll
  for (int i = 0; i < 2; ++i) {
    int g = i * 512 + tid * 2;  // 16B per thread per iter
    *(uint4*)&ldsA[g] = *(const uint4*)&Ag[g];
    *(uint4*)&ldsB[g] = *(const uint4*)&Bg[g];
  }
  __syncthreads();

  const int r16 = lane & 15;
  const int kg  = lane >> 4;

  long long qfrag[2][4], kfrag[2][4];
#pragma unroll
  for (int ks = 0; ks < 2; ++ks) {
#pragma unroll
    for (int f = 0; f < 4; ++f) {
      qfrag[ks][f] = ldsA[((wm * 4 + f) * 2 + ks) * 64 + lane];
      kfrag[ks][f] = ldsB[((wn * 4 + f) * 2 + ks) * 64 + lane];
    }
  }

  f32x4 acc[4][4] = {};  // [i = m-frag][j = n-frag]
#pragma unroll
  for (int ks = 0; ks < 2; ++ks)
#pragma unroll
    for (int i = 0; i < 4; ++i)
#pragma unroll
      for (int j = 0; j < 4; ++j)
        acc[i][j] = __builtin_amdgcn_mfma_f32_16x16x32_fp8_fp8(kfrag[ks][i], qfrag[ks][j],
                                                               acc[i][j], 0, 0, 0);

  // dequant: S = (raw fp8 dot) * amax_q*amax_k/(448^2) / sqrt(64)
  const float aq = fmaxf(__uint_as_float(amaxbits[0]), 1e-12f);
  const float ak = fmaxf(__uint_as_float(amaxbits[1]), 1e-12f);
  const float dq = aq * ak / (FP8_MAX * FP8_MAX * 8.0f);

  float* outbh = out + (size_t)bh * NS * NS;
#pragma unroll
  for (int j = 0; j < 4; ++j) {
    const int n = n0 + wm * 64 + j * 16 + r16;
#pragma unroll
    for (int i = 0; i < 4; ++i) {
      const int m = m0 + wn * 64 + i * 16 + kg * 4;
      f32x4 v;
#pragma unroll
      for (int r = 0; r < 4; ++r) v[r] = acc[i][j][r] * dq;
      *(f32x4*)(outbh + (size_t)n * NS + m) = v;
    }
  }
}

// ---------------------------------------------------------------------------
extern "C" void kernel_launch(void* const* d_in, const int* in_sizes, int n_in,
                              void* d_out, int out_size, void* d_ws, size_t ws_size,
                              hipStream_t stream) {
  const float* q = (const float*)d_in[0];
  const float* k = (const float*)d_in[1];
  float* out = (float*)d_out;

  // ws layout: [0..7] amax bits (q,k) | @256: fp8 Qp (8MB) | fp8 Kp (8MB)
  unsigned* amax = (unsigned*)d_ws;
  unsigned char* qp = (unsigned char*)d_ws + 256;
  unsigned char* kp = qp + (size_t)NB * NH * NS * ND;  // 8,388,608

  hipMemsetAsync(amax, 0, 8, stream);

  const int n4 = in_sizes[0] / 4;  // float4 count per tensor

  // Per-tensor ordering: quant_X immediately follows amax_X so the 134MB
  // tensor is still L3-resident (256MB) for the re-read.
  amax_kernel<<<1024, 256, 0, stream>>>(q, amax, n4);
  quant_kernel<<<4096, 256, 0, stream>>>(q, (uint2*)qp, amax);
  amax_kernel<<<1024, 256, 0, stream>>>(k, amax + 1, n4);
  quant_kernel<<<4096, 256, 0, stream>>>(k, (uint2*)kp, amax + 1);

  dim3 grid(NS / 128, NS / 128, NB * NH);  // (m-tiles, n-tiles, bh)
  gemm_kernel<<<grid, 256, 0, stream>>>((const long long*)qp, (const long long*)kp, out, amax);
}